// Round 6
// baseline (81.753 us; speedup 1.0000x reference)
//
#include <hip/hip_runtime.h>

#define NR 65536
#define RPB 4   // rays per 256-thread block (one wave per ray, waves fully independent)

typedef float f32x4 __attribute__((ext_vector_type(4)));

// Inclusive wave64 prefix-sum step via DPP (VALU pipe, no LDS traffic).
#define SCAN_STEP(ctrl, rmask)                                                  \
    do {                                                                        \
        int _t = __builtin_amdgcn_update_dpp(0, __float_as_int(sc),             \
                                             (ctrl), (rmask), 0xf, true);       \
        sc += __int_as_float(_t);                                               \
    } while (0)

// Must be bit-identical at every use site (merge consistency): one helper.
__device__ __forceinline__ float coarse_at(int j, float nr, float dnf) {
    return fmaf((float)j * (1.0f / 63.0f), dnf, nr);
}

__global__ __launch_bounds__(256) void ray_sampler_kernel(
    const float* __restrict__ origins,
    const float* __restrict__ directions,
    const float* __restrict__ nearv,
    const float* __restrict__ farv,
    const float* __restrict__ weights,
    float* __restrict__ out)
{
    __shared__ float s_cdf[RPB][64];     // entries 0..62 used
    __shared__ float s_fine[RPB][128];
    __shared__ float s_z[RPB][192];

    const int tid  = threadIdx.x;
    const int wv   = tid >> 6;
    const int lane = tid & 63;
    const int r    = blockIdx.x * RPB + wv;

    const float nr  = nearv[r];
    const float dnf = farv[r] - nr;

    float dx = directions[3*r+0];
    float dy = directions[3*r+1];
    float dz = directions[3*r+2];
    const float invn = 1.0f / sqrtf(dx*dx + dy*dy + dz*dz);
    dx *= invn; dy *= invn; dz *= invn;
    const float ox = origins[3*r+0];
    const float oy = origins[3*r+1];
    const float oz = origins[3*r+2];

    // ---- CDF from 62 interior weights via DPP wave scan (no ds_bpermute) ----
    float w = 0.0f;
    if (lane < 62) w = weights[(size_t)r*64 + lane + 1] + 1e-5f;
    float sc = w;
    SCAN_STEP(0x111, 0xf);   // row_shr:1
    SCAN_STEP(0x112, 0xf);   // row_shr:2
    SCAN_STEP(0x114, 0xf);   // row_shr:4
    SCAN_STEP(0x118, 0xf);   // row_shr:8
    SCAN_STEP(0x142, 0xa);   // row_bcast:15 -> rows 1,3
    SCAN_STEP(0x143, 0xc);   // row_bcast:31 -> rows 2,3
    const float total = __int_as_float(__builtin_amdgcn_readlane(__float_as_int(sc), 63));
    const float invT  = 1.0f / total;
    if (lane < 62) s_cdf[wv][lane + 1] = sc * invT;
    if (lane == 62) s_cdf[wv][0] = 0.0f;
    // No __syncthreads anywhere: each wave touches only its own LDS row.

    // ---- 128 fine samples; value-tracked search (no cdf[below/above] re-reads) ----
    const float* cdf = s_cdf[wv];
    float fv0, fv1;
    #pragma unroll
    for (int sIt = 0; sIt < 2; ++sIt) {
        const int s = lane + sIt * 64;
        const float u = (float)s * (1.0f/127.0f);
        int lo = 0, hi = 63;
        float vb = 0.0f, va = 1.0f;          // cdf[lo-1], cdf[hi] (virtual cdf[63]=1)
        #pragma unroll
        for (int it = 0; it < 6; ++it) {
            if (lo < hi) {
                const int mid = (lo + hi) >> 1;
                const float m = cdf[mid];
                if (m <= u) { lo = mid + 1; vb = m; }
                else        { hi = mid;     va = m; }
            }
        }
        const int below = (lo > 0) ? lo - 1 : 0;      // <= 62 by construction
        const int above = (lo > 62) ? 62 : lo;
        const float bb = fmaf(((float)below + 0.5f) * (1.0f/63.0f), dnf, nr);
        const float ba = fmaf(((float)above + 0.5f) * (1.0f/63.0f), dnf, nr);
        float den = va - vb;                  // when lo==63, ba==bb so den is irrelevant
        if (den < 1e-5f) den = 1.0f;
        const float tt = (u - vb) / den;
        const float fv = bb + tt * (ba - bb);
        s_fine[wv][s] = fv;
        if (sIt == 0) fv0 = fv; else fv1 = fv;
    }

    // ---- merge coarse(64, analytic) + fine(128, LDS) -> z(192) sorted ----
    const float* fine = s_fine[wv];
    {
        const float v = coarse_at(lane, nr, dnf);
        int lo = 0, hi = 128;                // count fine < v: 8 iters
        #pragma unroll
        for (int it = 0; it < 8; ++it) {
            if (lo < hi) {
                const int mid = (lo + hi) >> 1;
                if (fine[mid] < v) lo = mid + 1; else hi = mid;
            }
        }
        s_z[wv][lane + lo] = v;
    }
    #pragma unroll
    for (int sIt = 0; sIt < 2; ++sIt) {
        const float v = (sIt == 0) ? fv0 : fv1;
        int lo = 0, hi = 64;                 // count coarse <= v: 7 iters, pure VALU
        #pragma unroll
        for (int it = 0; it < 7; ++it) {
            if (lo < hi) {
                const int mid = (lo + hi) >> 1;
                if (coarse_at(mid, nr, dnf) <= v) lo = mid + 1; else hi = mid;
            }
        }
        s_z[wv][lane + sIt * 64 + lo] = v;
    }

    // ---- outputs ----
    const float* zw = s_z[wv];
    float* posb = out + (size_t)r * 576;
    float* vdb  = out + (size_t)NR * 576  + (size_t)r * 576;
    float* zb   = out + (size_t)NR * 1152 + (size_t)r * 192;
    float* dlb  = out + (size_t)NR * 1344 + (size_t)r * 192;

    // z + deltas: one ds_read_b128 + one b32, two NT dwordx4 stores
    if (lane < 48) {
        const f32x4 zq = *reinterpret_cast<const f32x4*>(&zw[4 * lane]);
        const int nx = (lane == 47) ? 190 : (4 * lane + 4);
        const float znx = zw[nx];
        f32x4 dl;
        dl[0] = zq[1] - zq[0];
        dl[1] = zq[2] - zq[1];
        dl[2] = zq[3] - zq[2];
        dl[3] = (lane == 47) ? (zq[3] - zq[2]) : (znx - zq[3]);
        __builtin_nontemporal_store(zq, reinterpret_cast<f32x4*>(zb) + lane);
        __builtin_nontemporal_store(dl, reinterpret_cast<f32x4*>(dlb) + lane);
    }

    // positions + viewdirs: recomputed per float4 from a z-pair (no LDS staging).
    // float4 q spans exactly samples k0=(4q)/3 and k0+1; p = 4q mod 3 = (lane+qi) mod 3.
    f32x4* pos4 = reinterpret_cast<f32x4*>(posb);
    f32x4* vd4  = reinterpret_cast<f32x4*>(vdb);
    const int l3 = lane % 3;
    #pragma unroll
    for (int qi = 0; qi < 3; ++qi) {
        if (qi < 2 || lane < 16) {
            const int q = lane + qi * 64;
            int p = l3 + qi; p -= (p >= 3) ? 3 : 0;
            const int k0 = (4 * q - p) / 3;          // exact division
            const float z0 = zw[k0];
            const float z1 = zw[k0 + 1];             // k0+1 <= 191
            f32x4 pv, vv;
            #pragma unroll
            for (int m = 0; m < 4; ++m) {
                int c = p + m; c -= (c >= 3) ? 3 : 0;
                const float dc = (c == 0) ? dx : ((c == 1) ? dy : dz);
                const float oc = (c == 0) ? ox : ((c == 1) ? oy : oz);
                const float zz = (p + m >= 3) ? z1 : z0;
                pv[m] = fmaf(zz, dc, oc);
                vv[m] = dc;
            }
            __builtin_nontemporal_store(pv, pos4 + q);
            __builtin_nontemporal_store(vv, vd4 + q);
        }
    }
}

extern "C" void kernel_launch(void* const* d_in, const int* in_sizes, int n_in,
                              void* d_out, int out_size, void* d_ws, size_t ws_size,
                              hipStream_t stream) {
    const float* origins    = (const float*)d_in[0];
    const float* directions = (const float*)d_in[1];
    const float* nearv      = (const float*)d_in[2];
    const float* farv       = (const float*)d_in[3];
    const float* weights    = (const float*)d_in[4];
    float* out = (float*)d_out;

    dim3 grid(NR / RPB);
    dim3 block(256);
    ray_sampler_kernel<<<grid, block, 0, stream>>>(origins, directions, nearv, farv, weights, out);
}